// Round 13
// baseline (314.322 us; speedup 1.0000x reference)
//
#include <hip/hip_runtime.h>
#include <hip/hip_bf16.h>

#define N_NODES   50000
#define N_EDGES   800000
#define N_GRAPHS  512
#define IN_DIM    128
#define HIDDEN    64
#define NPAD      50176          // 196 * 256, padded node count for scan
#define NBLK      196            // scan blocks
#define SHARD_BLOCKS 1024        // 128 blocks per shard x 8 shards

// ---------------------------------------------------------------------------
// XCD-sharded degree histogram: shard s owns nodes with ((d>>4)&7)==s, so
// every 64B line of degi is written from one shard (one XCD under %8 mapping).
__global__ __launch_bounds__(256) void k_degi_sh(const int* __restrict__ dst,
                                                 int* __restrict__ degi) {
    const int shard = blockIdx.x & 7;
    const int blk   = blockIdx.x >> 3;
    const int nthr  = (SHARD_BLOCKS >> 3) * 256;
    for (int e = blk * 256 + threadIdx.x; e < N_EDGES; e += nthr) {
        int d = dst[e];
        if (((d >> 4) & 7) == shard) atomicAdd(&degi[d], 1);
    }
}

// ---------------------------------------------------------------------------
// two-level exclusive scan over degi[NPAD] -> offs; also emits dinv (fused).
__global__ __launch_bounds__(256) void k_scan_block(const int* __restrict__ degi,
                                                    int* __restrict__ offs,
                                                    int* __restrict__ bsum,
                                                    float* __restrict__ dinv) {
    __shared__ int sh[256];
    int tid = threadIdx.x;
    int i = blockIdx.x * 256 + tid;
    int v = degi[i];
    dinv[i] = rsqrtf((float)v + 1.0f);         // fused dinv (pad rows harmless)
    sh[tid] = v;
    __syncthreads();
    #pragma unroll
    for (int off = 1; off < 256; off <<= 1) {
        int t = (tid >= off) ? sh[tid - off] : 0;
        __syncthreads();
        sh[tid] += t;
        __syncthreads();
    }
    offs[i] = sh[tid] - v;                     // exclusive
    if (tid == 255) bsum[blockIdx.x] = sh[tid];
}

__global__ __launch_bounds__(256) void k_scan_bsum(int* __restrict__ bsum,
                                                   int* __restrict__ boff) {
    __shared__ int sh[256];
    int tid = threadIdx.x;
    int v = (tid < NBLK) ? bsum[tid] : 0;
    sh[tid] = v;
    __syncthreads();
    #pragma unroll
    for (int off = 1; off < 256; off <<= 1) {
        int t = (tid >= off) ? sh[tid - off] : 0;
        __syncthreads();
        sh[tid] += t;
        __syncthreads();
    }
    if (tid < NBLK) boff[tid] = sh[tid] - v;   // exclusive block offsets
}

// adds block offsets AND seeds cnt with the final offs value, so k_fill_sh's
// atomicAdd(&cnt[d],1) returns the CSR slot directly (no offs read per edge).
__global__ __launch_bounds__(256) void k_scan_add(int* __restrict__ offs,
                                                  const int* __restrict__ boff,
                                                  int* __restrict__ cnt) {
    int i = blockIdx.x * 256 + threadIdx.x;
    int v = offs[i] + boff[blockIdx.x];
    offs[i] = v;
    cnt[i]  = v;
}

// XCD-sharded CSR fill: csr_src[atomicAdd(&cnt[d],1)] = src(e); src loaded
// only for matching edges.
__global__ __launch_bounds__(256) void k_fill_sh(const int* __restrict__ src,
                                                 const int* __restrict__ dst,
                                                 int* __restrict__ cnt,
                                                 int* __restrict__ csr_src) {
    const int shard = blockIdx.x & 7;
    const int blk   = blockIdx.x >> 3;
    const int nthr  = (SHARD_BLOCKS >> 3) * 256;
    for (int e = blk * 256 + threadIdx.x; e < N_EDGES; e += nthr) {
        int d = dst[e];
        if (((d >> 4) & 7) == shard) {
            int pos = atomicAdd(&cnt[d], 1);
            csr_src[pos] = src[e];
        }
    }
}

// ---------------------------------------------------------------------------
// Register-tiled GEMM (layer 1): out[N][64] = dinv[row] * ( A[N][128] @ W )
template <int K>
__global__ __launch_bounds__(256) void k_gemm64t(const float* __restrict__ A,
                                                 const float* __restrict__ W,
                                                 const float* __restrict__ dinv,
                                                 float* __restrict__ out) {
    __shared__ float sA[64][65];
    __shared__ float sW[64][64];

    const int tid = threadIdx.x;
    const int rowBase = blockIdx.x * 64;
    const int c0 = (tid & 15) * 4;
    const int r0 = (tid >> 4) * 4;

    float acc[4][4];
    #pragma unroll
    for (int j = 0; j < 4; ++j)
        #pragma unroll
        for (int c = 0; c < 4; ++c) acc[j][c] = 0.0f;

    for (int kc = 0; kc < K; kc += 64) {
        __syncthreads();
        #pragma unroll
        for (int p = 0; p < 4; ++p) {
            int i = p * 256 + tid;
            int k  = i >> 4;
            int cq = i & 15;
            *reinterpret_cast<float4*>(&sW[k][cq * 4]) =
                *reinterpret_cast<const float4*>(&W[(size_t)(kc + k) * 64 + cq * 4]);
        }
        #pragma unroll
        for (int p = 0; p < 4; ++p) {
            int i = p * 256 + tid;
            int row = i >> 4;
            int kq  = i & 15;
            int gr = rowBase + row;
            float4 v = make_float4(0.f, 0.f, 0.f, 0.f);
            if (gr < N_NODES)
                v = *reinterpret_cast<const float4*>(&A[(size_t)gr * K + kc + kq * 4]);
            sA[row][kq * 4 + 0] = v.x;
            sA[row][kq * 4 + 1] = v.y;
            sA[row][kq * 4 + 2] = v.z;
            sA[row][kq * 4 + 3] = v.w;
        }
        __syncthreads();

        #pragma unroll 8
        for (int k = 0; k < 64; ++k) {
            float4 w4 = *reinterpret_cast<const float4*>(&sW[k][c0]);
            float a0 = sA[r0 + 0][k];
            float a1 = sA[r0 + 1][k];
            float a2 = sA[r0 + 2][k];
            float a3 = sA[r0 + 3][k];
            acc[0][0] = fmaf(a0, w4.x, acc[0][0]);
            acc[0][1] = fmaf(a0, w4.y, acc[0][1]);
            acc[0][2] = fmaf(a0, w4.z, acc[0][2]);
            acc[0][3] = fmaf(a0, w4.w, acc[0][3]);
            acc[1][0] = fmaf(a1, w4.x, acc[1][0]);
            acc[1][1] = fmaf(a1, w4.y, acc[1][1]);
            acc[1][2] = fmaf(a1, w4.z, acc[1][2]);
            acc[1][3] = fmaf(a1, w4.w, acc[1][3]);
            acc[2][0] = fmaf(a2, w4.x, acc[2][0]);
            acc[2][1] = fmaf(a2, w4.y, acc[2][1]);
            acc[2][2] = fmaf(a2, w4.z, acc[2][2]);
            acc[2][3] = fmaf(a2, w4.w, acc[2][3]);
            acc[3][0] = fmaf(a3, w4.x, acc[3][0]);
            acc[3][1] = fmaf(a3, w4.y, acc[3][1]);
            acc[3][2] = fmaf(a3, w4.z, acc[3][2]);
            acc[3][3] = fmaf(a3, w4.w, acc[3][3]);
        }
    }

    #pragma unroll
    for (int j = 0; j < 4; ++j) {
        int gr = rowBase + r0 + j;
        if (gr < N_NODES) {
            float di = dinv[gr];
            float4 o;
            o.x = di * acc[j][0];
            o.y = di * acc[j][1];
            o.z = di * acc[j][2];
            o.w = di * acc[j][3];
            *reinterpret_cast<float4*>(&out[(size_t)gr * 64 + c0]) = o;
        }
    }
}

// ---------------------------------------------------------------------------
// Fused layer 2: gather (self + CSR neighbors of yw1) -> relu(+b1) staged in
// sA, then 64x64 register-tiled GEMM with W2, epilogue x dinv -> yw2 (agg).
__global__ __launch_bounds__(256) void k_gg(const int* __restrict__ csr_src,
                                            const int* __restrict__ offs,
                                            const int* __restrict__ degi,
                                            const float* __restrict__ dinv,
                                            const float* __restrict__ yw_in,
                                            const float* __restrict__ bin,
                                            const float* __restrict__ W,
                                            float* __restrict__ out) {
    __shared__ float sA[64][65];
    __shared__ float sW[64][64];
    __shared__ float sB[64];

    const int tid = threadIdx.x;
    const int rowBase = blockIdx.x * 64;

    // stage W2 + b1
    #pragma unroll
    for (int p = 0; p < 4; ++p) {
        int i = p * 256 + tid;
        int k  = i >> 4;
        int cq = i & 15;
        *reinterpret_cast<float4*>(&sW[k][cq * 4]) =
            *reinterpret_cast<const float4*>(&W[(size_t)k * 64 + cq * 4]);
    }
    if (tid < 64) sB[tid] = bin[tid];
    __syncthreads();

    // gather phase: wave w handles rows w*16 .. w*16+15
    const int wave = tid >> 6;
    const int lane = tid & 63;
    for (int j = 0; j < 16; ++j) {
        int r = wave * 16 + j;
        int node = rowBase + r;
        float val = 0.0f;
        if (node < N_NODES) {
            float acc = yw_in[(size_t)node * 64 + lane];   // self (pre-scaled)
            int beg = offs[node];
            int n   = degi[node];
            int q = 0;
            for (; q + 7 < n; q += 8) {
                int s[8];
                #pragma unroll
                for (int u = 0; u < 8; ++u) s[u] = csr_src[beg + q + u];
                float v[8];
                #pragma unroll
                for (int u = 0; u < 8; ++u) v[u] = yw_in[(size_t)s[u] * 64 + lane];
                #pragma unroll
                for (int u = 0; u < 8; ++u) acc += v[u];
            }
            for (; q < n; ++q) {
                int s = csr_src[beg + q];
                acc += yw_in[(size_t)s * 64 + lane];
            }
            val = fmaxf(dinv[node] * acc + sB[lane], 0.0f);  // relu(agg1+b1)
        }
        sA[r][lane] = val;
    }
    __syncthreads();

    // GEMM phase
    const int c0 = (tid & 15) * 4;
    const int r0 = (tid >> 4) * 4;
    float acc[4][4];
    #pragma unroll
    for (int j = 0; j < 4; ++j)
        #pragma unroll
        for (int c = 0; c < 4; ++c) acc[j][c] = 0.0f;

    #pragma unroll 8
    for (int k = 0; k < 64; ++k) {
        float4 w4 = *reinterpret_cast<const float4*>(&sW[k][c0]);
        float a0 = sA[r0 + 0][k];
        float a1 = sA[r0 + 1][k];
        float a2 = sA[r0 + 2][k];
        float a3 = sA[r0 + 3][k];
        acc[0][0] = fmaf(a0, w4.x, acc[0][0]);
        acc[0][1] = fmaf(a0, w4.y, acc[0][1]);
        acc[0][2] = fmaf(a0, w4.z, acc[0][2]);
        acc[0][3] = fmaf(a0, w4.w, acc[0][3]);
        acc[1][0] = fmaf(a1, w4.x, acc[1][0]);
        acc[1][1] = fmaf(a1, w4.y, acc[1][1]);
        acc[1][2] = fmaf(a1, w4.z, acc[1][2]);
        acc[1][3] = fmaf(a1, w4.w, acc[1][3]);
        acc[2][0] = fmaf(a2, w4.x, acc[2][0]);
        acc[2][1] = fmaf(a2, w4.y, acc[2][1]);
        acc[2][2] = fmaf(a2, w4.z, acc[2][2]);
        acc[2][3] = fmaf(a2, w4.w, acc[2][3]);
        acc[3][0] = fmaf(a3, w4.x, acc[3][0]);
        acc[3][1] = fmaf(a3, w4.y, acc[3][1]);
        acc[3][2] = fmaf(a3, w4.z, acc[3][2]);
        acc[3][3] = fmaf(a3, w4.w, acc[3][3]);
    }

    #pragma unroll
    for (int j = 0; j < 4; ++j) {
        int gr = rowBase + r0 + j;
        if (gr < N_NODES) {
            float di = dinv[gr];
            float4 o;
            o.x = di * acc[j][0];
            o.y = di * acc[j][1];
            o.z = di * acc[j][2];
            o.w = di * acc[j][3];
            *reinterpret_cast<float4*>(&out[(size_t)gr * 64 + c0]) = o;
        }
    }
}

// ---------------------------------------------------------------------------
// Fused layer 3: wave-per-node gather of yw2 -> relu(+b2) -> @W3[64][2] via
// shuffle reduce -> x dinv -> yw3[node][2].
__global__ __launch_bounds__(256) void k_gyw3(const int* __restrict__ csr_src,
                                              const int* __restrict__ offs,
                                              const int* __restrict__ degi,
                                              const float* __restrict__ dinv,
                                              const float* __restrict__ yw_in,
                                              const float* __restrict__ b2,
                                              const float* __restrict__ W3,
                                              float* __restrict__ yw3) {
    __shared__ float sW[128];
    __shared__ float sB[64];
    int tid = threadIdx.x;
    if (tid < 128) sW[tid] = W3[tid];
    if (tid < 64)  sB[tid] = b2[tid];
    __syncthreads();

    int node = blockIdx.x * 4 + (tid >> 6);
    int lane = tid & 63;
    if (node >= N_NODES) return;

    float acc = yw_in[(size_t)node * 64 + lane];   // self (pre-scaled)
    int beg = offs[node];
    int n   = degi[node];
    int q = 0;
    for (; q + 7 < n; q += 8) {
        int s[8];
        #pragma unroll
        for (int u = 0; u < 8; ++u) s[u] = csr_src[beg + q + u];
        float v[8];
        #pragma unroll
        for (int u = 0; u < 8; ++u) v[u] = yw_in[(size_t)s[u] * 64 + lane];
        #pragma unroll
        for (int u = 0; u < 8; ++u) acc += v[u];
    }
    for (; q < n; ++q) {
        int s = csr_src[beg + q];
        acc += yw_in[(size_t)s * 64 + lane];
    }

    float z  = fmaxf(dinv[node] * acc + sB[lane], 0.0f);   // relu(agg2+b2)
    float p0 = z * sW[lane * 2 + 0];
    float p1 = z * sW[lane * 2 + 1];
    #pragma unroll
    for (int off = 32; off >= 1; off >>= 1) {
        p0 += __shfl_xor(p0, off);
        p1 += __shfl_xor(p1, off);
    }
    if (lane == 0) {
        float di = dinv[node];
        yw3[(size_t)node * 2 + 0] = di * p0;
        yw3[(size_t)node * 2 + 1] = di * p1;
    }
}

// ---------------------------------------------------------------------------
// Fused final gather + pooling (batch sorted -> LDS bins, few global atomics).
__global__ __launch_bounds__(256) void k_gather2pool(const int* __restrict__ csr_src,
                                                     const int* __restrict__ offs,
                                                     const int* __restrict__ degi,
                                                     const float* __restrict__ dinv,
                                                     const float* __restrict__ yw,
                                                     const int* __restrict__ batch,
                                                     float* __restrict__ psum,
                                                     float* __restrict__ pcnt) {
    __shared__ float ls0[N_GRAPHS];
    __shared__ float ls1[N_GRAPHS];
    __shared__ float lc [N_GRAPHS];
    int tid = threadIdx.x;
    #pragma unroll
    for (int g = tid; g < N_GRAPHS; g += 256) {
        ls0[g] = 0.f; ls1[g] = 0.f; lc[g] = 0.f;
    }
    __syncthreads();

    int node = blockIdx.x * 256 + tid;
    if (node < N_NODES) {
        float2 v = *reinterpret_cast<const float2*>(&yw[(size_t)node * 2]);
        float a0 = v.x, a1 = v.y;
        int beg = offs[node];
        int n   = degi[node];
        for (int j = 0; j < n; ++j) {
            int s = csr_src[beg + j];
            float2 u = *reinterpret_cast<const float2*>(&yw[(size_t)s * 2]);
            a0 += u.x;
            a1 += u.y;
        }
        float di = dinv[node];
        int g = batch[node];
        atomicAdd(&ls0[g], di * a0);
        atomicAdd(&ls1[g], di * a1);
        atomicAdd(&lc [g], 1.0f);
    }
    __syncthreads();

    #pragma unroll
    for (int g = tid; g < N_GRAPHS; g += 256) {
        float c = lc[g];
        if (c != 0.0f) {
            atomicAdd(&psum[g * 2 + 0], ls0[g]);
            atomicAdd(&psum[g * 2 + 1], ls1[g]);
            atomicAdd(&pcnt[g], c);
        }
    }
}

__global__ __launch_bounds__(256) void k_final(const float* __restrict__ psum,
                                               const float* __restrict__ pcnt,
                                               const float* __restrict__ b3,
                                               float* __restrict__ out) {
    int g = blockIdx.x * 256 + threadIdx.x;
    if (g >= N_GRAPHS) return;
    float c  = pcnt[g];
    float cc = fmaxf(c, 1.0f);
    out[g * 2 + 0] = (psum[g * 2 + 0] + c * b3[0]) / cc;
    out[g * 2 + 1] = (psum[g * 2 + 1] + c * b3[1]) / cc;
}

// ---------------------------------------------------------------------------
extern "C" void kernel_launch(void* const* d_in, const int* in_sizes, int n_in,
                              void* d_out, int out_size, void* d_ws, size_t ws_size,
                              hipStream_t stream) {
    const float* x     = (const float*)d_in[0];
    const int*   ei    = (const int*)d_in[1];
    const int*   batch = (const int*)d_in[2];
    const float* W1    = (const float*)d_in[3];
    const float* b1    = (const float*)d_in[4];
    const float* W2    = (const float*)d_in[5];
    const float* b2    = (const float*)d_in[6];
    const float* W3    = (const float*)d_in[7];
    const float* b3    = (const float*)d_in[8];
    const int* src = ei;
    const int* dst = ei + N_EDGES;

    float* ws   = (float*)d_ws;
    float* dinv = ws;                            // NPAD floats
    int*   degi = (int*)(dinv + NPAD);           // NPAD
    int*   offs = degi + NPAD;                   // NPAD
    int*   cnt  = offs + NPAD;                   // NPAD
    int*   bsum = cnt + NPAD;                    // 256
    int*   boff = bsum + 256;                    // 256
    int*   csr  = boff + 256;                    // N_EDGES
    float* xw   = (float*)(csr + N_EDGES);       // 3,200,000  (yw1, later yw3)
    float* agg  = xw + (size_t)N_NODES * 64;     // 3,200,000  (yw2)
    float* psum = agg + (size_t)N_NODES * 64;    // 1024
    float* pcnt = psum + 1024;                   // 512
    float* out  = (float*)d_out;

    hipMemsetAsync(degi, 0, NPAD * sizeof(int), stream);
    hipMemsetAsync(psum, 0, (1024 + 512) * sizeof(float), stream);

    // ---- graph preprocessing: degrees (+dinv fused in scan), CSR
    k_degi_sh<<<SHARD_BLOCKS, 256, 0, stream>>>(dst, degi);
    k_scan_block<<<NBLK, 256, 0, stream>>>(degi, offs, bsum, dinv);
    k_scan_bsum<<<1, 256, 0, stream>>>(bsum, boff);
    k_scan_add<<<NBLK, 256, 0, stream>>>(offs, boff, cnt);
    k_fill_sh<<<SHARD_BLOCKS, 256, 0, stream>>>(src, dst, cnt, csr);

    // ---- layer 1: yw1 = dinv * (x @ W1)
    k_gemm64t<128><<<(N_NODES + 63) / 64, 256, 0, stream>>>(x, W1, dinv, xw);

    // ---- layer 2 (fused gather+GEMM): yw2 = dinv * (relu(A_hat yw1 + b1) @ W2)
    k_gg<<<(N_NODES + 63) / 64, 256, 0, stream>>>(csr, offs, degi, dinv, xw, b1, W2, agg);

    // ---- layer 3 (fused gather+proj): yw3 = dinv * (relu(A_hat yw2 + b2) @ W3)
    k_gyw3<<<(N_NODES + 3) / 4, 256, 0, stream>>>(csr, offs, degi, dinv, agg, b2, W3, xw);

    // ---- final aggregation + pooling
    k_gather2pool<<<(N_NODES + 255) / 256, 256, 0, stream>>>(csr, offs, degi, dinv, xw,
                                                             batch, psum, pcnt);
    k_final<<<(N_GRAPHS + 255) / 256, 256, 0, stream>>>(psum, pcnt, b3, out);
}

// Round 14
// 296.787 us; speedup vs baseline: 1.0591x; 1.0591x over previous
//
#include <hip/hip_runtime.h>
#include <hip/hip_bf16.h>

#define N_NODES   50000
#define N_EDGES   800000
#define N_GRAPHS  512
#define IN_DIM    128
#define HIDDEN    64
#define NPAD      50176          // 196 * 256, padded node count for scan
#define NBLK      196            // scan blocks
#define SHARD_BLOCKS 1024        // 128 blocks per shard x 8 shards

// ---------------------------------------------------------------------------
// XCD-sharded degree histogram: shard s owns nodes with ((d>>4)&7)==s.
__global__ __launch_bounds__(256) void k_degi_sh(const int* __restrict__ dst,
                                                 int* __restrict__ degi) {
    const int shard = blockIdx.x & 7;
    const int blk   = blockIdx.x >> 3;
    const int nthr  = (SHARD_BLOCKS >> 3) * 256;
    for (int e = blk * 256 + threadIdx.x; e < N_EDGES; e += nthr) {
        int d = dst[e];
        if (((d >> 4) & 7) == shard) atomicAdd(&degi[d], 1);
    }
}

// ---------------------------------------------------------------------------
// two-level exclusive scan over degi[NPAD] -> offs; also emits dinv (fused).
__global__ __launch_bounds__(256) void k_scan_block(const int* __restrict__ degi,
                                                    int* __restrict__ offs,
                                                    int* __restrict__ bsum,
                                                    float* __restrict__ dinv) {
    __shared__ int sh[256];
    int tid = threadIdx.x;
    int i = blockIdx.x * 256 + tid;
    int v = degi[i];
    dinv[i] = rsqrtf((float)v + 1.0f);
    sh[tid] = v;
    __syncthreads();
    #pragma unroll
    for (int off = 1; off < 256; off <<= 1) {
        int t = (tid >= off) ? sh[tid - off] : 0;
        __syncthreads();
        sh[tid] += t;
        __syncthreads();
    }
    offs[i] = sh[tid] - v;
    if (tid == 255) bsum[blockIdx.x] = sh[tid];
}

__global__ __launch_bounds__(256) void k_scan_bsum(int* __restrict__ bsum,
                                                   int* __restrict__ boff) {
    __shared__ int sh[256];
    int tid = threadIdx.x;
    int v = (tid < NBLK) ? bsum[tid] : 0;
    sh[tid] = v;
    __syncthreads();
    #pragma unroll
    for (int off = 1; off < 256; off <<= 1) {
        int t = (tid >= off) ? sh[tid - off] : 0;
        __syncthreads();
        sh[tid] += t;
        __syncthreads();
    }
    if (tid < NBLK) boff[tid] = sh[tid] - v;
}

__global__ __launch_bounds__(256) void k_scan_add(int* __restrict__ offs,
                                                  const int* __restrict__ boff,
                                                  int* __restrict__ cnt) {
    int i = blockIdx.x * 256 + threadIdx.x;
    int v = offs[i] + boff[blockIdx.x];
    offs[i] = v;
    cnt[i]  = v;
}

// XCD-sharded CSR fill; src loaded only for matching edges.
__global__ __launch_bounds__(256) void k_fill_sh(const int* __restrict__ src,
                                                 const int* __restrict__ dst,
                                                 int* __restrict__ cnt,
                                                 int* __restrict__ csr_src) {
    const int shard = blockIdx.x & 7;
    const int blk   = blockIdx.x >> 3;
    const int nthr  = (SHARD_BLOCKS >> 3) * 256;
    for (int e = blk * 256 + threadIdx.x; e < N_EDGES; e += nthr) {
        int d = dst[e];
        if (((d >> 4) & 7) == shard) {
            int pos = atomicAdd(&cnt[d], 1);
            csr_src[pos] = src[e];
        }
    }
}

// ---------------------------------------------------------------------------
// Register-tiled GEMM: out[N][64] = dinv[row] * ( f(A)[N][K] @ W[K][64] ),
// f = identity or relu(x + bin).  64x64 tile, 4x4 micro-tile per thread.
template <int K, bool RELU_IN>
__global__ __launch_bounds__(256) void k_gemm64t(const float* __restrict__ A,
                                                 const float* __restrict__ W,
                                                 const float* __restrict__ bin,
                                                 const float* __restrict__ dinv,
                                                 float* __restrict__ out) {
    __shared__ float sA[64][65];
    __shared__ float sW[64][64];
    __shared__ float sB[64];

    const int tid = threadIdx.x;
    const int rowBase = blockIdx.x * 64;
    const int c0 = (tid & 15) * 4;
    const int r0 = (tid >> 4) * 4;

    if (RELU_IN && tid < 64) sB[tid] = bin[tid];

    float acc[4][4];
    #pragma unroll
    for (int j = 0; j < 4; ++j)
        #pragma unroll
        for (int c = 0; c < 4; ++c) acc[j][c] = 0.0f;

    for (int kc = 0; kc < K; kc += 64) {
        __syncthreads();
        #pragma unroll
        for (int p = 0; p < 4; ++p) {
            int i = p * 256 + tid;
            int k  = i >> 4;
            int cq = i & 15;
            *reinterpret_cast<float4*>(&sW[k][cq * 4]) =
                *reinterpret_cast<const float4*>(&W[(size_t)(kc + k) * 64 + cq * 4]);
        }
        #pragma unroll
        for (int p = 0; p < 4; ++p) {
            int i = p * 256 + tid;
            int row = i >> 4;
            int kq  = i & 15;
            int gr = rowBase + row;
            float4 v = make_float4(0.f, 0.f, 0.f, 0.f);
            if (gr < N_NODES)
                v = *reinterpret_cast<const float4*>(&A[(size_t)gr * K + kc + kq * 4]);
            if (RELU_IN) {
                v.x = fmaxf(v.x + sB[kq * 4 + 0], 0.f);
                v.y = fmaxf(v.y + sB[kq * 4 + 1], 0.f);
                v.z = fmaxf(v.z + sB[kq * 4 + 2], 0.f);
                v.w = fmaxf(v.w + sB[kq * 4 + 3], 0.f);
            }
            sA[row][kq * 4 + 0] = v.x;
            sA[row][kq * 4 + 1] = v.y;
            sA[row][kq * 4 + 2] = v.z;
            sA[row][kq * 4 + 3] = v.w;
        }
        __syncthreads();

        #pragma unroll 8
        for (int k = 0; k < 64; ++k) {
            float4 w4 = *reinterpret_cast<const float4*>(&sW[k][c0]);
            float a0 = sA[r0 + 0][k];
            float a1 = sA[r0 + 1][k];
            float a2 = sA[r0 + 2][k];
            float a3 = sA[r0 + 3][k];
            acc[0][0] = fmaf(a0, w4.x, acc[0][0]);
            acc[0][1] = fmaf(a0, w4.y, acc[0][1]);
            acc[0][2] = fmaf(a0, w4.z, acc[0][2]);
            acc[0][3] = fmaf(a0, w4.w, acc[0][3]);
            acc[1][0] = fmaf(a1, w4.x, acc[1][0]);
            acc[1][1] = fmaf(a1, w4.y, acc[1][1]);
            acc[1][2] = fmaf(a1, w4.z, acc[1][2]);
            acc[1][3] = fmaf(a1, w4.w, acc[1][3]);
            acc[2][0] = fmaf(a2, w4.x, acc[2][0]);
            acc[2][1] = fmaf(a2, w4.y, acc[2][1]);
            acc[2][2] = fmaf(a2, w4.z, acc[2][2]);
            acc[2][3] = fmaf(a2, w4.w, acc[2][3]);
            acc[3][0] = fmaf(a3, w4.x, acc[3][0]);
            acc[3][1] = fmaf(a3, w4.y, acc[3][1]);
            acc[3][2] = fmaf(a3, w4.z, acc[3][2]);
            acc[3][3] = fmaf(a3, w4.w, acc[3][3]);
        }
    }

    #pragma unroll
    for (int j = 0; j < 4; ++j) {
        int gr = rowBase + r0 + j;
        if (gr < N_NODES) {
            float di = dinv[gr];
            float4 o;
            o.x = di * acc[j][0];
            o.y = di * acc[j][1];
            o.z = di * acc[j][2];
            o.w = di * acc[j][3];
            *reinterpret_cast<float4*>(&out[(size_t)gr * 64 + c0]) = o;
        }
    }
}

// out[N][2] = dinv[i] * ( relu(A + b2) @ W3[64][2] )
__global__ __launch_bounds__(256) void k_gemm2(const float* __restrict__ A,
                                               const float* __restrict__ W3,
                                               const float* __restrict__ b2,
                                               const float* __restrict__ dinv,
                                               float* __restrict__ out) {
    __shared__ float sW[128];
    __shared__ float sB[64];
    int tid = threadIdx.x;
    if (tid < 128) sW[tid] = W3[tid];
    if (tid < 64)  sB[tid] = b2[tid];
    __syncthreads();
    int i = blockIdx.x * 256 + tid;
    if (i >= N_NODES) return;
    float a0 = 0.f, a1 = 0.f;
    const float* row = A + (size_t)i * 64;
    #pragma unroll
    for (int k = 0; k < 64; k += 4) {
        float4 v = *reinterpret_cast<const float4*>(row + k);
        float z;
        z = fmaxf(v.x + sB[k + 0], 0.f); a0 = fmaf(z, sW[(k+0)*2+0], a0); a1 = fmaf(z, sW[(k+0)*2+1], a1);
        z = fmaxf(v.y + sB[k + 1], 0.f); a0 = fmaf(z, sW[(k+1)*2+0], a0); a1 = fmaf(z, sW[(k+1)*2+1], a1);
        z = fmaxf(v.z + sB[k + 2], 0.f); a0 = fmaf(z, sW[(k+2)*2+0], a0); a1 = fmaf(z, sW[(k+2)*2+1], a1);
        z = fmaxf(v.w + sB[k + 3], 0.f); a0 = fmaf(z, sW[(k+3)*2+0], a0); a1 = fmaf(z, sW[(k+3)*2+1], a1);
    }
    float di = dinv[i];
    out[i * 2 + 0] = di * a0;
    out[i * 2 + 1] = di * a1;
}

// ---------------------------------------------------------------------------
// gather aggregation D=64: one wave per node, lane = feature dim.  Standalone
// (8 VGPR, no LDS) for max occupancy — latency-bound random gather needs TLP.
__global__ __launch_bounds__(256) void k_gather64(const int* __restrict__ csr_src,
                                                  const int* __restrict__ offs,
                                                  const int* __restrict__ degi,
                                                  const float* __restrict__ dinv,
                                                  const float* __restrict__ yw,
                                                  float* __restrict__ agg) {
    int gid  = blockIdx.x * 256 + threadIdx.x;
    int node = gid >> 6;
    int lane = threadIdx.x & 63;
    if (node >= N_NODES) return;
    float acc = yw[(size_t)node * 64 + lane];   // self-loop term (pre-scaled)
    int beg = offs[node];
    int n   = degi[node];
    int j = 0;
    for (; j + 7 < n; j += 8) {
        int s[8];
        #pragma unroll
        for (int u = 0; u < 8; ++u) s[u] = csr_src[beg + j + u];
        float v[8];
        #pragma unroll
        for (int u = 0; u < 8; ++u) v[u] = yw[(size_t)s[u] * 64 + lane];
        #pragma unroll
        for (int u = 0; u < 8; ++u) acc += v[u];
    }
    for (; j < n; ++j) {
        int s = csr_src[beg + j];
        acc += yw[(size_t)s * 64 + lane];
    }
    agg[(size_t)node * 64 + lane] = dinv[node] * acc;
}

// ---------------------------------------------------------------------------
// Fused final gather + pooling (batch sorted -> LDS bins, few global atomics).
__global__ __launch_bounds__(256) void k_gather2pool(const int* __restrict__ csr_src,
                                                     const int* __restrict__ offs,
                                                     const int* __restrict__ degi,
                                                     const float* __restrict__ dinv,
                                                     const float* __restrict__ yw,
                                                     const int* __restrict__ batch,
                                                     float* __restrict__ psum,
                                                     float* __restrict__ pcnt) {
    __shared__ float ls0[N_GRAPHS];
    __shared__ float ls1[N_GRAPHS];
    __shared__ float lc [N_GRAPHS];
    int tid = threadIdx.x;
    #pragma unroll
    for (int g = tid; g < N_GRAPHS; g += 256) {
        ls0[g] = 0.f; ls1[g] = 0.f; lc[g] = 0.f;
    }
    __syncthreads();

    int node = blockIdx.x * 256 + tid;
    if (node < N_NODES) {
        float2 v = *reinterpret_cast<const float2*>(&yw[(size_t)node * 2]);
        float a0 = v.x, a1 = v.y;
        int beg = offs[node];
        int n   = degi[node];
        for (int j = 0; j < n; ++j) {
            int s = csr_src[beg + j];
            float2 u = *reinterpret_cast<const float2*>(&yw[(size_t)s * 2]);
            a0 += u.x;
            a1 += u.y;
        }
        float di = dinv[node];
        int g = batch[node];
        atomicAdd(&ls0[g], di * a0);
        atomicAdd(&ls1[g], di * a1);
        atomicAdd(&lc [g], 1.0f);
    }
    __syncthreads();

    #pragma unroll
    for (int g = tid; g < N_GRAPHS; g += 256) {
        float c = lc[g];
        if (c != 0.0f) {
            atomicAdd(&psum[g * 2 + 0], ls0[g]);
            atomicAdd(&psum[g * 2 + 1], ls1[g]);
            atomicAdd(&pcnt[g], c);
        }
    }
}

__global__ __launch_bounds__(256) void k_final(const float* __restrict__ psum,
                                               const float* __restrict__ pcnt,
                                               const float* __restrict__ b3,
                                               float* __restrict__ out) {
    int g = blockIdx.x * 256 + threadIdx.x;
    if (g >= N_GRAPHS) return;
    float c  = pcnt[g];
    float cc = fmaxf(c, 1.0f);
    out[g * 2 + 0] = (psum[g * 2 + 0] + c * b3[0]) / cc;
    out[g * 2 + 1] = (psum[g * 2 + 1] + c * b3[1]) / cc;
}

// ---------------------------------------------------------------------------
extern "C" void kernel_launch(void* const* d_in, const int* in_sizes, int n_in,
                              void* d_out, int out_size, void* d_ws, size_t ws_size,
                              hipStream_t stream) {
    const float* x     = (const float*)d_in[0];
    const int*   ei    = (const int*)d_in[1];
    const int*   batch = (const int*)d_in[2];
    const float* W1    = (const float*)d_in[3];
    const float* b1    = (const float*)d_in[4];
    const float* W2    = (const float*)d_in[5];
    const float* b2    = (const float*)d_in[6];
    const float* W3    = (const float*)d_in[7];
    const float* b3    = (const float*)d_in[8];
    const int* src = ei;
    const int* dst = ei + N_EDGES;

    float* ws   = (float*)d_ws;
    float* dinv = ws;                            // NPAD floats
    int*   degi = (int*)(dinv + NPAD);           // NPAD
    int*   offs = degi + NPAD;                   // NPAD
    int*   cnt  = offs + NPAD;                   // NPAD
    int*   bsum = cnt + NPAD;                    // 256
    int*   boff = bsum + 256;                    // 256
    int*   csr  = boff + 256;                    // N_EDGES
    float* xw   = (float*)(csr + N_EDGES);       // 3,200,000  (yw1, later yw3)
    float* agg  = xw + (size_t)N_NODES * 64;     // 3,200,000  (agg1/agg2)
    float* psum = agg + (size_t)N_NODES * 64;    // 1024
    float* pcnt = psum + 1024;                   // 512
    float* out  = (float*)d_out;

    hipMemsetAsync(degi, 0, NPAD * sizeof(int), stream);
    hipMemsetAsync(psum, 0, (1024 + 512) * sizeof(float), stream);

    // ---- graph preprocessing: degrees (+dinv fused in scan), CSR
    k_degi_sh<<<SHARD_BLOCKS, 256, 0, stream>>>(dst, degi);
    k_scan_block<<<NBLK, 256, 0, stream>>>(degi, offs, bsum, dinv);
    k_scan_bsum<<<1, 256, 0, stream>>>(bsum, boff);
    k_scan_add<<<NBLK, 256, 0, stream>>>(offs, boff, cnt);
    k_fill_sh<<<SHARD_BLOCKS, 256, 0, stream>>>(src, dst, cnt, csr);

    // ---- layer 1: yw1 = dinv * (x @ W1); agg1 = dinv * (self + gather)
    k_gemm64t<128, false><<<(N_NODES + 63) / 64, 256, 0, stream>>>(x, W1, nullptr, dinv, xw);
    k_gather64<<<(N_NODES * 64) / 256, 256, 0, stream>>>(csr, offs, degi, dinv, xw, agg);

    // ---- layer 2: yw2 = dinv * (relu(agg1+b1) @ W2); agg2 = ...
    k_gemm64t<64, true><<<(N_NODES + 63) / 64, 256, 0, stream>>>(agg, W2, b1, dinv, xw);
    k_gather64<<<(N_NODES * 64) / 256, 256, 0, stream>>>(csr, offs, degi, dinv, xw, agg);

    // ---- layer 3: yw3 = dinv * (relu(agg2+b2) @ W3); fused gather+pool
    k_gemm2<<<(N_NODES + 255) / 256, 256, 0, stream>>>(agg, W3, b2, dinv, xw);
    k_gather2pool<<<(N_NODES + 255) / 256, 256, 0, stream>>>(csr, offs, degi, dinv, xw,
                                                             batch, psum, pcnt);

    // ---- final
    k_final<<<(N_GRAPHS + 255) / 256, 256, 0, stream>>>(psum, pcnt, b3, out);
}